// Round 2
// baseline (2797.876 us; speedup 1.0000x reference)
//
#include <hip/hip_runtime.h>
#include <math.h>

// Problem constants (fixed by setup_inputs).
#define TT 16384
#define HH 4096
#define EE 256

// GEMM tiling: 64x64 block tile, BK=32, 256 threads, 4x4 per-thread tile.
// Grid = (TT/64)*(EE/64) = 1024 blocks = 4 blocks/CU -> 16 waves/CU.
#define BM 64
#define BN 64
#define BK 32

// ---------------------------------------------------------------------------
// CAS-based double atomic add (no dependence on -munsafe-fp-atomics).
__device__ inline void atom_add_double(double* addr, double val) {
    unsigned long long* p = (unsigned long long*)addr;
    unsigned long long old = *p, assumed;
    do {
        assumed = old;
        double nv = __longlong_as_double(assumed) + val;
        old = atomicCAS(p, assumed, __double_as_longlong(nv));
    } while (old != assumed);
}

__global__ __launch_bounds__(64) void zero_ws_kernel(double* z) {
    if (threadIdx.x == 0) *z = 0.0;
}

// ---------------------------------------------------------------------------
// Fused fp32 GEMM (raw = x @ W^T) + sigmoid + z-loss partial reduction.
// LDS is stored k-major (transposed) so compute reads are ds_read_b128.
__global__ __launch_bounds__(256) void gemm_sigmoid_kernel(
    const float* __restrict__ x,      // (TT, HH) row-major
    const float* __restrict__ w,      // (EE, HH) row-major
    float* __restrict__ logits,       // (TT, EE)  (only 4B-aligned!)
    double* __restrict__ zacc)
{
    __shared__ float As[BK][BM];      // [k][m]
    __shared__ float Bs[BK][BN];      // [k][e]
    __shared__ float zred[256];

    const int tid  = threadIdx.x;
    const int nb   = blockIdx.x & 3;        // n-block fastest: 4 blocks share
    const int mb   = blockIdx.x >> 2;       //   the same x slab (L2/L3 reuse)
    const int row0 = mb * BM;
    const int col0 = nb * BN;
    const int tx   = tid & 15;              // 0..15 -> cols tx*4..tx*4+3
    const int ty   = tid >> 4;              // 0..15 -> rows ty*4..ty*4+3
    const int lm   = tid & 63;              // loader row / expert
    const int lk   = (tid >> 6) << 2;       // 0,4,8,12 (float4 along k)

    const float* xp = x + (size_t)(row0 + lm) * HH + lk;
    const float* wp = w + (size_t)(col0 + lm) * HH + lk;

    float acc[4][4];
#pragma unroll
    for (int i = 0; i < 4; ++i)
#pragma unroll
        for (int j = 0; j < 4; ++j) acc[i][j] = 0.f;

    // Stage slab 0 into registers.
    float4 xa0 = *(const float4*)(xp);
    float4 xa1 = *(const float4*)(xp + 16);
    float4 wb0 = *(const float4*)(wp);
    float4 wb1 = *(const float4*)(wp + 16);

    int k0 = 0;
    for (;;) {
        __syncthreads();   // previous tile's LDS reads are done
        As[lk + 0][lm] = xa0.x;  As[lk + 1][lm] = xa0.y;
        As[lk + 2][lm] = xa0.z;  As[lk + 3][lm] = xa0.w;
        As[lk + 16][lm] = xa1.x; As[lk + 17][lm] = xa1.y;
        As[lk + 18][lm] = xa1.z; As[lk + 19][lm] = xa1.w;
        Bs[lk + 0][lm] = wb0.x;  Bs[lk + 1][lm] = wb0.y;
        Bs[lk + 2][lm] = wb0.z;  Bs[lk + 3][lm] = wb0.w;
        Bs[lk + 16][lm] = wb1.x; Bs[lk + 17][lm] = wb1.y;
        Bs[lk + 18][lm] = wb1.z; Bs[lk + 19][lm] = wb1.w;
        __syncthreads();

        k0 += BK;
        if (k0 < HH) {
            // Prefetch next slab; latency hides under the compute below.
            xa0 = *(const float4*)(xp + k0);
            xa1 = *(const float4*)(xp + k0 + 16);
            wb0 = *(const float4*)(wp + k0);
            wb1 = *(const float4*)(wp + k0 + 16);
        }

#pragma unroll
        for (int kk = 0; kk < BK; ++kk) {
            const float4 a = *(const float4*)&As[kk][ty << 2];
            const float4 b = *(const float4*)&Bs[kk][tx << 2];
            const float av[4] = {a.x, a.y, a.z, a.w};
            const float bv[4] = {b.x, b.y, b.z, b.w};
#pragma unroll
            for (int i = 0; i < 4; ++i)
#pragma unroll
                for (int j = 0; j < 4; ++j)
                    acc[i][j] = fmaf(av[i], bv[j], acc[i][j]);
        }
        if (k0 >= HH) break;
    }

    // Epilogue: z-loss partial + sigmoid + store logits (scalar: 4B-aligned).
    float zs = 0.f;
#pragma unroll
    for (int i = 0; i < 4; ++i) {
        const int r = row0 + (ty << 2) + i;
        float* lp = logits + (size_t)r * EE + col0 + (tx << 2);
#pragma unroll
        for (int j = 0; j < 4; ++j) {
            const float v = acc[i][j];
            zs = fmaf(v, v, zs);
            lp[j] = 1.f / (1.f + expf(-v));
        }
    }
    zred[tid] = zs;
    __syncthreads();
    for (int s = 128; s > 0; s >>= 1) {
        if (tid < s) zred[tid] += zred[tid + s];
        __syncthreads();
    }
    if (tid == 0) atom_add_double(zacc, (double)zred[0]);
}

// ---------------------------------------------------------------------------
// Router: one wave (64 lanes) per token; lane l owns experts 4l..4l+3.
// Matches jax.lax.top_k stability: ties broken toward the LOWER index.
// Block 0 / thread 255 also finalizes z_loss (router runs after the GEMM).
__global__ __launch_bounds__(256) void router_kernel(
    const float* __restrict__ logits,   // (TT, EE) sigmoid scores
    const float* __restrict__ bias,     // (EE)
    float* __restrict__ wout,           // (TT, 8)
    float* __restrict__ iout,           // (TT, 8) indices stored as float
    const double* __restrict__ zacc,
    float* __restrict__ zout)
{
    if (blockIdx.x == 0 && threadIdx.x == 255)
        *zout = (float)(*zacc / (double)((size_t)TT * (size_t)EE));

    const int lane = threadIdx.x & 63;
    const int wv   = threadIdx.x >> 6;
    const int t    = blockIdx.x * 4 + wv;

    // logits region of d_out is only 4B-aligned -> scalar loads.
    const float* lrow = logits + (size_t)t * EE + lane * 4;
    float lg[4];
#pragma unroll
    for (int q = 0; q < 4; ++q) lg[q] = lrow[q];
    const float4 b4 = *(const float4*)(bias + lane * 4);
    const float bb[4] = {b4.x, b4.y, b4.z, b4.w};

    float sel[4];
#pragma unroll
    for (int q = 0; q < 4; ++q) sel[q] = lg[q] + bb[q];

    // ---- group score: sum of top-2 of the 32 experts in this lane's group.
    float m1 = sel[0], m2 = -INFINITY;
#pragma unroll
    for (int q = 1; q < 4; ++q) {
        if (sel[q] > m1) { m2 = m1; m1 = sel[q]; }
        else             { m2 = fmaxf(m2, sel[q]); }
    }
#pragma unroll
    for (int d = 1; d < 8; d <<= 1) {
        const float o1 = __shfl_xor(m1, d);
        const float o2 = __shfl_xor(m2, d);
        const float nm1 = fmaxf(m1, o1);
        const float nm2 = fmaxf(fminf(m1, o1), fmaxf(m2, o2));
        m1 = nm1; m2 = nm2;
    }
    const float gs = m1 + m2;
    const int g = lane >> 3;

    // ---- stable rank of this group's score among the 8 groups.
    int rank = 0;
#pragma unroll
    for (int gp = 0; gp < 8; ++gp) {
        const float og = __shfl(gs, gp << 3);
        rank += (og > gs) || (og == gs && gp < g);
    }
    const bool keep = rank < 4;  // TOPK_GROUP = 4

    float ms[4];
#pragma unroll
    for (int q = 0; q < 4; ++q)
        ms[q] = keep ? sel[q] : -3.402823466e38f;  // finfo(f32).min

    // ---- iterative top-8 with (value desc, index asc) wave argmax.
    float wvals[8];
    int   widx[8];
#pragma unroll
    for (int it = 0; it < 8; ++it) {
        float bv = ms[0];
        int bq = 0;
#pragma unroll
        for (int q = 1; q < 4; ++q)
            if (ms[q] > bv) { bv = ms[q]; bq = q; }   // strict > keeps low q
        int   bi = (lane << 2) + bq;
        float bl = lg[bq];
#pragma unroll
        for (int d = 1; d < 64; d <<= 1) {
            const float ov = __shfl_xor(bv, d);
            const int   oi = __shfl_xor(bi, d);
            const float ol = __shfl_xor(bl, d);
            if (ov > bv || (ov == bv && oi < bi)) { bv = ov; bi = oi; bl = ol; }
        }
        wvals[it] = bl;   // combine weight = raw sigmoid (bias-free)
        widx[it]  = bi;
        if ((bi >> 2) == lane) ms[bi & 3] = -INFINITY;  // owner invalidates
    }

    float s = 0.f;
#pragma unroll
    for (int it = 0; it < 8; ++it) s += wvals[it];
    s = fmaxf(s, 1e-9f);

    if (lane == 0) {
#pragma unroll
        for (int it = 0; it < 8; ++it) {
            wout[(size_t)t * 8 + it] = wvals[it] / s;
            iout[(size_t)t * 8 + it] = (float)widx[it];
        }
    }
}

// ---------------------------------------------------------------------------
extern "C" void kernel_launch(void* const* d_in, const int* in_sizes, int n_in,
                              void* d_out, int out_size, void* d_ws, size_t ws_size,
                              hipStream_t stream) {
    const float* x    = (const float*)d_in[0];   // (TT, HH)
    const float* w    = (const float*)d_in[1];   // (EE, HH)
    const float* bias = (const float*)d_in[2];   // (EE)

    float* out    = (float*)d_out;
    float* wout   = out;                      // weights: TT*8
    float* iout   = out + (size_t)TT * 8;     // indices (as float): TT*8
    float* zout   = out + (size_t)TT * 16;    // z_loss: 1
    float* logits = zout + 1;                 // logits: TT*EE
    double* zacc  = (double*)d_ws;

    zero_ws_kernel<<<1, 64, 0, stream>>>(zacc);
    gemm_sigmoid_kernel<<<(TT / BM) * (EE / BN), 256, 0, stream>>>(x, w, logits, zacc);
    router_kernel<<<TT / 4, 256, 0, stream>>>(logits, bias, wout, iout, zacc, zout);
}